// Round 6
// baseline (64.960 us; speedup 1.0000x reference)
//
#include <hip/hip_runtime.h>

#define NPG 148      // nodes per graph
#define EPG 592      // edges per graph
#define NTHR 256
#define SA   40      // f16 stride of A16/Wt rows (32 + 8 pad); 80 B
#define MT   10      // M row-tiles (148 -> 160 padded)

typedef _Float16 h8 __attribute__((ext_vector_type(8)));
typedef _Float16 h4 __attribute__((ext_vector_type(4)));
typedef float    f4 __attribute__((ext_vector_type(4)));

__device__ __forceinline__ float f16bits_to_f32(unsigned short u) {
    return (float)__builtin_bit_cast(_Float16, u);
}

// One block = one graph.
//   G: agg[d] = dis[d]*(dis[d]*h[d] + sum_{s->d} dis[s]*h[s])
//      thread <-> node, all KC column-chunks per thread, pipelined CSR walk
//   M: h' = relu(agg @ W + b) via v_mfma_f32_16x16x32_f16
// s_csr[e] = srcByteOff | disF16<<16

template<int Fi, int Fo, int KC, int NTN, int MAXJ, int WROW, int BOFF, bool LAST>
__device__ __forceinline__ void layer(int t,
    _Float16* __restrict__ A16, const _Float16* __restrict__ Wt,
    const _Float16* __restrict__ s_bh, const unsigned int* __restrict__ s_csr,
    const unsigned short* __restrict__ s_row, const unsigned short* __restrict__ s_dis,
    float* __restrict__ gout)
{
    // ---- Phase G: per-thread node, KC-wide accumulate, pipelined csr reads ----
    float a[KC][8];
    if (t < NPG) {
        const float dd = f16bits_to_f32(s_dis[t]);
        const char* selfb = reinterpret_cast<const char*>(A16) + t * (SA * 2);
        #pragma unroll
        for (int kc = 0; kc < KC; ++kc) {
            const h8 hv = *reinterpret_cast<const h8*>(selfb + kc * 16);
            #pragma unroll
            for (int u = 0; u < 8; ++u) a[kc][u] = dd * (float)hv[u];
        }
        int e  = s_row[t];
        const int e1 = s_row[t + 1];
        unsigned int pk = (e < e1) ? s_csr[e] : 0u;
        while (e < e1) {
            const unsigned int pknext = (e + 1 < e1) ? s_csr[e + 1] : 0u;
            const char* mb = reinterpret_cast<const char*>(A16) + (pk & 0xffffu);
            const float ds = f16bits_to_f32((unsigned short)(pk >> 16));
            #pragma unroll
            for (int kc = 0; kc < KC; ++kc) {
                const h8 m = *reinterpret_cast<const h8*>(mb + kc * 16);
                #pragma unroll
                for (int u = 0; u < 8; ++u) a[kc][u] = fmaf((float)m[u], ds, a[kc][u]);
            }
            pk = pknext;
            ++e;
        }
        #pragma unroll
        for (int kc = 0; kc < KC; ++kc)
            #pragma unroll
            for (int u = 0; u < 8; ++u) a[kc][u] *= dd;
    }
    __syncthreads();
    if (t < NPG) {
        char* selfb = reinterpret_cast<char*>(A16) + t * (SA * 2);
        #pragma unroll
        for (int kc = 0; kc < KC; ++kc) {
            h8 pv;
            #pragma unroll
            for (int u = 0; u < 8; ++u) pv[u] = (_Float16)a[kc][u];
            *reinterpret_cast<h8*>(selfb + kc * 16) = pv;
        }
    }
    __syncthreads();

    // ---- Phase M: MFMA. Pre-load fragments, barrier, compute+write ----
    const int w   = t >> 6;
    const int l16 = t & 15;
    const int q   = (t >> 4) & 3;
    h8 af[MAXJ], bf[MAXJ];
    #pragma unroll
    for (int j = 0; j < MAXJ; ++j) {
        const int idx = w + 4 * j;
        if (idx < MT * NTN) {
            const int mt = idx / NTN, nt = idx % NTN;
            af[j] = *reinterpret_cast<const h8*>(&A16[(mt * 16 + l16) * SA + q * 8]);
            bf[j] = *reinterpret_cast<const h8*>(&Wt[(WROW + nt * 16 + l16) * SA + q * 8]);
        }
    }
    __syncthreads();
    #pragma unroll
    for (int j = 0; j < MAXJ; ++j) {
        const int idx = w + 4 * j;
        if (idx < MT * NTN) {
            const int mt = idx / NTN, nt = idx % NTN;
            f4 acc = {0.f, 0.f, 0.f, 0.f};
            acc = __builtin_amdgcn_mfma_f32_16x16x32_f16(af[j], bf[j], acc, 0, 0, 0);
            const int col  = nt * 16 + l16;
            const float bias = (float)s_bh[BOFF + col];
            #pragma unroll
            for (int rr = 0; rr < 4; ++rr) {
                const float v = fmaxf(acc[rr] + bias, 0.f);
                const int row = mt * 16 + q * 4 + rr;
                if (LAST) {
                    if (row < NPG) gout[row * 64 + col] = v;
                } else {
                    A16[row * SA + col] = (_Float16)v;
                }
            }
        }
    }
    if (!LAST) __syncthreads();
}

__global__ __launch_bounds__(256, 6)
void gcn_fused(const float* __restrict__ x,
               const int* __restrict__ esrc, const int* __restrict__ edst,
               const float* __restrict__ W1, const float* __restrict__ b1,
               const float* __restrict__ W2, const float* __restrict__ b2,
               const float* __restrict__ W3, const float* __restrict__ b3,
               float* __restrict__ out)
{
    __shared__ __align__(16) _Float16 A16[160 * SA];     // 12800 B
    __shared__ __align__(16) _Float16 Wt[112 * SA];      // 8960 B (s_edge overlays head)
    __shared__ _Float16 s_bh[112];                       // 224 B
    __shared__ unsigned int s_csr[EPG];                  // 2368 B
    __shared__ unsigned short s_row[152];                // 304 B
    __shared__ unsigned short s_dis[NPG];                // 296 B
    __shared__ int s_cnt[NPG], s_cnt2[NPG];              // 1184 B
    // total ~26.2 KB -> 6 blocks/CU

    int* s_edge = reinterpret_cast<int*>(Wt);            // overlay (dead before Wt staged)

    const int t  = threadIdx.x;
    const int g  = blockIdx.x;
    const int be = g * EPG;
    const int bn = g * NPG;

    // ---- P0: zero counters, load edges (packed, localized) ----
    if (t < NPG) { s_cnt[t] = 0; s_cnt2[t] = 0; }
    for (int e = t; e < EPG; e += NTHR) {
        const int s = esrc[be + e] - bn;
        const int d = edst[be + e] - bn;
        s_edge[e] = s | (d << 8);
    }
    __syncthreads();

    // ---- P1: in-degree count ----
    for (int e = t; e < EPG; e += NTHR)
        atomicAdd(&s_cnt[((unsigned)s_edge[e]) >> 8], 1);
    __syncthreads();

    // ---- P2: dis (f16) + wave-0 shfl prefix scan -> u16 row offsets ----
    if (t < NPG) {
        const float disf = rsqrtf((float)(s_cnt[t] + 1));
        s_dis[t] = __builtin_bit_cast(unsigned short, (_Float16)disf);
    }
    if (t < 64) {
        const int lane = t;
        int v0 = s_cnt[lane];
        int v1 = s_cnt[64 + lane];
        int v2 = (128 + lane < NPG) ? s_cnt[128 + lane] : 0;
        #pragma unroll
        for (int off = 1; off < 64; off <<= 1) {
            const int u0 = __shfl_up(v0, off);
            const int u1 = __shfl_up(v1, off);
            const int u2 = __shfl_up(v2, off);
            if (lane >= off) { v0 += u0; v1 += u1; v2 += u2; }
        }
        const int t0 = __shfl(v0, 63);
        const int t1 = __shfl(v1, 63);
        v1 += t0;
        v2 += t0 + t1;
        if (lane == 0) s_row[0] = 0;
        s_row[1 + lane]  = (unsigned short)v0;
        s_row[65 + lane] = (unsigned short)v1;
        if (128 + lane < NPG) s_row[129 + lane] = (unsigned short)v2;
    }
    __syncthreads();

    // ---- P3: scatter packed CSR entries (srcByteOff | disF16<<16) ----
    for (int e = t; e < EPG; e += NTHR) {
        const int pk = s_edge[e];
        const int s  = pk & 0xFF;
        const int d  = (unsigned)pk >> 8;
        const int pos = (int)s_row[d] + atomicAdd(&s_cnt2[d], 1);
        s_csr[pos] = (unsigned int)(s * (SA * 2)) | ((unsigned int)s_dis[s] << 16);
    }
    __syncthreads();

    // ---- P4: zero A16/Wt (K/M padding must be 0), stage W^T f16, bias, x ----
    for (int i = t; i < 160 * SA / 8; i += NTHR) reinterpret_cast<f4*>(A16)[i] = f4{0.f, 0.f, 0.f, 0.f};
    for (int i = t; i < 112 * SA / 8; i += NTHR) reinterpret_cast<f4*>(Wt)[i]  = f4{0.f, 0.f, 0.f, 0.f};
    __syncthreads();
    for (int i = t; i < 64;   i += NTHR) Wt[(i & 15) * SA + (i >> 4)]        = (_Float16)W1[i];
    for (int i = t; i < 512;  i += NTHR) Wt[(16 + (i & 31)) * SA + (i >> 5)] = (_Float16)W2[i];
    for (int i = t; i < 2048; i += NTHR) Wt[(48 + (i & 63)) * SA + (i >> 6)] = (_Float16)W3[i];
    if (t < 16)       s_bh[t] = (_Float16)b1[t];
    else if (t < 48)  s_bh[t] = (_Float16)b2[t - 16];
    else if (t < 112) s_bh[t] = (_Float16)b3[t - 48];
    if (t < NPG) {
        const float4 xv = reinterpret_cast<const float4*>(x)[bn + t];
        h4 p; p[0] = (_Float16)xv.x; p[1] = (_Float16)xv.y; p[2] = (_Float16)xv.z; p[3] = (_Float16)xv.w;
        *reinterpret_cast<h4*>(&A16[t * SA]) = p;
    }
    __syncthreads();

    float* gout = out + (size_t)bn * 64;
    //     Fi  Fo  KC NTN MAXJ WROW BOFF LAST
    layer< 4, 16,  1,  1,   3,    0,   0, false>(t, A16, Wt, s_bh, s_csr, s_row, s_dis, gout);
    layer<16, 32,  2,  2,   5,   16,  16, false>(t, A16, Wt, s_bh, s_csr, s_row, s_dis, gout);
    layer<32, 64,  4,  4,  10,   48,  48, true >(t, A16, Wt, s_bh, s_csr, s_row, s_dis, gout);
}

extern "C" void kernel_launch(void* const* d_in, const int* in_sizes, int n_in,
                              void* d_out, int out_size, void* d_ws, size_t ws_size,
                              hipStream_t stream)
{
    const float* x  = (const float*)d_in[0];
    const int*   ei = (const int*)d_in[1];
    const float* W1 = (const float*)d_in[3];
    const float* b1 = (const float*)d_in[4];
    const float* W2 = (const float*)d_in[5];
    const float* b2 = (const float*)d_in[6];
    const float* W3 = (const float*)d_in[7];
    const float* b3 = (const float*)d_in[8];
    float* out = (float*)d_out;

    const int N = in_sizes[0] / 4;     // total nodes
    const int B = N / NPG;             // graphs
    const int E = in_sizes[1] / 2;     // total edges

    gcn_fused<<<B, NTHR, 0, stream>>>(x, ei, ei + E, W1, b1, W2, b2, W3, b3, out);
}